// Round 4
// baseline (284.237 us; speedup 1.0000x reference)
//
#include <hip/hip_runtime.h>
#include <math.h>

// LSTM B=1024,T=512,IN=16,H=64,OUT=8, gates i,f,g,o.
// R16: CHAIN SCHEDULE. R14/R15 proved wall = 512 x single-wave dependency
// chain (~1110cyc): R14 (1 wave/SIMD, half work) == R15 (2 waves, 2x work)
// == ~237us. Co-residency adds throughput, not wall. Only the one wave's
// in-order dep path counts. R13 (1060cyc, fastest) differed from R15 by
// x-MFMA placement: its 4 x-MFMAs sat right after the ds_reads, filling
// the ~120cyc LDS read latency; R15 left that stall naked.
//   1) x-part MFMAs at step top (fill read stall; no cross-step accX regs;
//      consumed directly as C-in by the first K-half h-MFMAs).
//   2) independent K-halves: second-half h-MFMAs use a pinned ZERO tile as
//      C-in (D!=C legal), halves recombined with 1 scalar add post-sel4.
//      Removes a dependent-MFMA latency link (~40cyc) from each gate group
//      at +6 VALU issue.
//   3) kept: DPP lane^8 gate-pairing (6 trans/step), symmetric both-halves
//      cs/h update (merged same-addr writes, conflict-free), act scales
//      folded into fp16 weights (i,f,o x -L2E; g x +L2E2; cs = L2E2*c),
//      setprio(1) over the trans tail, dbuf h LDS, 1 lite barrier/step,
//      x prefetched 2 steps ahead, 2 blocks/CU.

#define LSTM_T 512
#define LSTM_IN 16
#define LSTM_H 64
#define LSTM_OUT 8
#define BT 2
#define HSTRIDE 80   // halves per batch row; 160B stride = +8 banks

#define L2E   1.44269504088896340736f
#define L2E2  2.88539008177792681472f

typedef _Float16 half8  __attribute__((ext_vector_type(8)));
typedef float    floatx4 __attribute__((ext_vector_type(4)));

static __device__ __forceinline__ float fast_rcp(float x) { return __builtin_amdgcn_rcpf(x); }
static __device__ __forceinline__ float fast_exp2(float x) { return __builtin_amdgcn_exp2f(x); }
// p pre-scaled by log2e:
static __device__ __forceinline__ float sigm2(float p) { return fast_rcp(1.0f + fast_exp2(-p)); }
static __device__ __forceinline__ void pin4(int4& v) {
    asm volatile("" : "+v"(v.x), "+v"(v.y), "+v"(v.z), "+v"(v.w));
}
static __device__ __forceinline__ void pinf4(float4& v) {
    asm volatile("" : "+v"(v.x), "+v"(v.y), "+v"(v.z), "+v"(v.w));
}
static __device__ __forceinline__ void lite_barrier() {
    asm volatile("s_waitcnt lgkmcnt(0)\n\ts_barrier" ::: "memory");
}
static __device__ __forceinline__ unsigned pk2h(float a, float b) {
    return __builtin_bit_cast(unsigned, __builtin_amdgcn_cvt_pkrtz(a, b));
}
static __device__ __forceinline__ half8 to_h8(float4 a, float4 b) {
    uint4 u = make_uint4(pk2h(a.x, a.y), pk2h(a.z, a.w), pk2h(b.x, b.y), pk2h(b.z, b.w));
    return __builtin_bit_cast(half8, u);
}
static __device__ __forceinline__ int4 cvt8h(float4 a, float4 b) {
    return __builtin_bit_cast(int4, to_h8(a, b));
}
static __device__ __forceinline__ float4 ld4(const float* p) {
    return *reinterpret_cast<const float4*>(p);
}
static __device__ __forceinline__ float4 scl4(float4 v, float s) {
    return make_float4(s * v.x, s * v.y, s * v.z, s * v.w);
}
static __device__ __forceinline__ float sel4(floatx4 v, bool r0, bool r1) {
    float lo = r0 ? v[1] : v[0];
    float hi = r0 ? v[3] : v[2];
    return r1 ? hi : lo;
}
// exchange with lane^8 via DPP row_ror:8 (16-lane rows): two-way swap,
// full-rate VALU, no LDS pipe, no lgkmcnt involvement.
static __device__ __forceinline__ float dpp8(float v) {
    int r = __builtin_amdgcn_update_dpp(0, __builtin_bit_cast(int, v),
                                        0x128, 0xF, 0xF, false);
    return __builtin_bit_cast(float, r);
}

__global__ __launch_bounds__(256, 2)
void lstm_mfma_kernel(const float* __restrict__ x,
                      const float* __restrict__ W_ih,
                      const float* __restrict__ W_hh,
                      const float* __restrict__ b_ih,
                      const float* __restrict__ b_hh,
                      const float* __restrict__ W_fc,
                      const float* __restrict__ b_fc,
                      float* __restrict__ out) {
    const int tid   = threadIdx.x;
    const int lane  = tid & 63;
    const int w     = tid >> 6;        // wave -> j-slice [16w, 16w+16)
    const int q     = lane >> 4;       // k-quad / C row group
    const int m     = lane & 15;       // A row-in-tile / B col / C col
    const int b     = m & 1;           // real batch (cols = 2 b x 8 replicas)
    const int rho   = (m >> 1) & 3;    // replica id -> C row r to activate
    const bool r0   = (rho & 1) != 0;
    const bool r1   = (rho & 2) != 0;
    const bool h1   = (m & 8) != 0;    // gate-pair half: 0 = f/i, 1 = g/o
    const int jmine = 16 * w + 4 * q + rho;   // this lane's hidden index
    const int bbase = blockIdx.x * BT;

    // unified activation: act1 = a1 + b1*rcp(1+exp2(u1)), scales pre-folded
    // in weights: half0 u1 = -L2E*f_pre (sigma); half1 u1 = L2E2*g_pre (tanh)
    const float a1 = h1 ? 1.0f : 0.0f;
    const float b1 = h1 ? -2.0f : 1.0f;

    __shared__ __align__(128) _Float16 hbuf[2][BT][HSTRIDE]; // h state, dbuf
    __shared__ __align__(16)  float    hfin[BT][LSTM_H];     // final h for FC

    // ---- weights as pinned fp16 A-fragments, act scales PRE-FOLDED ----
    // tile tt = gate type (0=i,1=f,2=g,3=o); A row = tt*64 + 16w + m.
    int4 Ah[4][2], Ax[4];
    float4 bias4[4];
    #pragma unroll
    for (int tt = 0; tt < 4; ++tt) {
        const float sc = (tt == 2) ? L2E2 : -L2E;
        const int gt = tt * 64 + 16 * w + m;
        #pragma unroll
        for (int c = 0; c < 2; ++c) {
            const float* s = W_hh + gt * LSTM_H + 32 * c + 8 * q;
            Ah[tt][c] = cvt8h(scl4(ld4(s), sc), scl4(ld4(s + 4), sc));
            pin4(Ah[tt][c]);
        }
        float4 xa = make_float4(0.f, 0.f, 0.f, 0.f), xb = xa;
        if (q < 2) {
            const float* s = W_ih + gt * LSTM_IN + 8 * q;
            xa = ld4(s); xb = ld4(s + 4);
        }
        Ax[tt] = cvt8h(scl4(xa, sc), scl4(xb, sc));
        pin4(Ax[tt]);
        const int gb = tt * 64 + 16 * w + 4 * q;
        float4 bi = ld4(b_ih + gb), bh = ld4(b_hh + gb);
        bias4[tt] = make_float4(sc * (bi.x + bh.x), sc * (bi.y + bh.y),
                                sc * (bi.z + bh.z), sc * (bi.w + bh.w));
        pinf4(bias4[tt]);
    }

    // ---- pinned zero C-tile for independent second K-half MFMAs ----
    float4 zc4 = make_float4(0.f, 0.f, 0.f, 0.f);
    pinf4(zc4);
    const floatx4 zc = __builtin_bit_cast(floatx4, zc4);

    // ---- zero hbuf[0] (h_{-1} = 0): 2 batches * 80 halves = 80 dwords ----
    if (tid < 80) {
        reinterpret_cast<int*>(&hbuf[0][0][0])[tid] = 0;
    }

    // ---- x: lane covers batch b, elements 8q..8q+7 (q<2 real) ----
    const float* xp = x + (size_t)(bbase + b) * LSTM_T * LSTM_IN + 8 * q;
    float4 xA0 = make_float4(0.f, 0.f, 0.f, 0.f), xA1 = xA0;  // even steps
    float4 xB0 = xA0, xB1 = xA0;                              // odd steps
    if (q < 2) {
        xA0 = ld4(xp);              xA1 = ld4(xp + 4);               // x_0
        xB0 = ld4(xp + LSTM_IN);    xB1 = ld4(xp + LSTM_IN + 4);     // x_1
    }
    __syncthreads();   // hbuf zeros visible

    float cs = 0.0f, hreg = 0.0f;   // cs = L2E2 * c (pre-scaled cell)

#define STEP(T_, X0, X1)                                                        \
    {                                                                           \
        const _Float16* cur = &hbuf[(T_) & 1][0][0];                            \
        _Float16*       nxt = &hbuf[((T_) + 1) & 1][0][0];                      \
        /* on-chain loads: issue first */                                       \
        half8 bh0 = *reinterpret_cast<const half8*>(cur + b * HSTRIDE + 8 * q); \
        half8 bh1 = *reinterpret_cast<const half8*>(cur + b * HSTRIDE + 32 + 8 * q); \
        /* x-part MFMAs fill the ~120cyc LDS read latency (R13 placement) */    \
        half8 xf = to_h8(X0, X1);                                               \
        floatx4 aXi = __builtin_amdgcn_mfma_f32_16x16x32_f16(                   \
            __builtin_bit_cast(half8, Ax[0]), xf,                               \
            __builtin_bit_cast(floatx4, bias4[0]), 0, 0, 0);                    \
        floatx4 aXf = __builtin_amdgcn_mfma_f32_16x16x32_f16(                   \
            __builtin_bit_cast(half8, Ax[1]), xf,                               \
            __builtin_bit_cast(floatx4, bias4[1]), 0, 0, 0);                    \
        floatx4 aXg = __builtin_amdgcn_mfma_f32_16x16x32_f16(                   \
            __builtin_bit_cast(half8, Ax[2]), xf,                               \
            __builtin_bit_cast(floatx4, bias4[2]), 0, 0, 0);                    \
        floatx4 aXo = __builtin_amdgcn_mfma_f32_16x16x32_f16(                   \
            __builtin_bit_cast(half8, Ax[3]), xf,                               \
            __builtin_bit_cast(floatx4, bias4[3]), 0, 0, 0);                    \
        /* reload this x reg set with x_{t+2} (global, off-chain) */            \
        if (q < 2 && (T_) + 2 < LSTM_T) {                                       \
            X0 = ld4(xp + (size_t)((T_) + 2) * LSTM_IN);                        \
            X1 = ld4(xp + (size_t)((T_) + 2) * LSTM_IN + 4);                    \
        }                                                                       \
        /* f,g gates: 4 INDEPENDENT MFMAs (second K-half takes zero C) */       \
        floatx4 afA = __builtin_amdgcn_mfma_f32_16x16x32_f16(                   \
            __builtin_bit_cast(half8, Ah[1][0]), bh0, aXf, 0, 0, 0);            \
        floatx4 agA = __builtin_amdgcn_mfma_f32_16x16x32_f16(                   \
            __builtin_bit_cast(half8, Ah[2][0]), bh0, aXg, 0, 0, 0);            \
        floatx4 afB = __builtin_amdgcn_mfma_f32_16x16x32_f16(                   \
            __builtin_bit_cast(half8, Ah[1][1]), bh1, zc, 0, 0, 0);             \
        floatx4 agB = __builtin_amdgcn_mfma_f32_16x16x32_f16(                   \
            __builtin_bit_cast(half8, Ah[2][1]), bh1, zc, 0, 0, 0);             \
        __builtin_amdgcn_s_setprio(1);                                          \
        float uf = sel4(afA, r0, r1) + sel4(afB, r0, r1);                       \
        float ug = sel4(agA, r0, r1) + sel4(agB, r0, r1);                       \
        float u1 = h1 ? ug : uf;                                                \
        float e1 = fast_exp2(u1);                                               \
        /* i,o gates issue under e1's latency */                                \
        floatx4 aiA = __builtin_amdgcn_mfma_f32_16x16x32_f16(                   \
            __builtin_bit_cast(half8, Ah[0][0]), bh0, aXi, 0, 0, 0);            \
        floatx4 aoA = __builtin_amdgcn_mfma_f32_16x16x32_f16(                   \
            __builtin_bit_cast(half8, Ah[3][0]), bh0, aXo, 0, 0, 0);            \
        floatx4 aiB = __builtin_amdgcn_mfma_f32_16x16x32_f16(                   \
            __builtin_bit_cast(half8, Ah[0][1]), bh1, zc, 0, 0, 0);             \
        floatx4 aoB = __builtin_amdgcn_mfma_f32_16x16x32_f16(                   \
            __builtin_bit_cast(half8, Ah[3][1]), bh1, zc, 0, 0, 0);             \
        float act1 = fmaf(b1, fast_rcp(1.0f + e1), a1);                         \
        float ui = sel4(aiA, r0, r1) + sel4(aiB, r0, r1);                       \
        float uo = sel4(aoA, r0, r1) + sel4(aoB, r0, r1);                       \
        float u2 = h1 ? uo : ui;                                                \
        float act2 = fast_rcp(1.0f + fast_exp2(u2));                            \
        /* two-way DPP swap with lane^8 */                                      \
        float g_in = dpp8(act1);                                                \
        float o_in = dpp8(act2);                                                \
        /* symmetric roles: both halves compute identical valid cs/h */         \
        float fsel = h1 ? g_in : act1;   /* sigma(f) */                         \
        float isel = h1 ? o_in : act2;   /* sigma(i) */                         \
        float gsel = h1 ? act1 : g_in;   /* tanh(g)  */                         \
        float osel = h1 ? act2 : o_in;   /* sigma(o) */                         \
        cs = fmaf(fsel, cs, (L2E2 * isel) * gsel);                              \
        float th = fmaf(-2.0f, fast_rcp(1.0f + fast_exp2(cs)), 1.0f);           \
        hreg = osel * th;                                                       \
        /* unconditional write: pair lanes hit same b16 addr, same value */     \
        nxt[b * HSTRIDE + jmine] = (_Float16)hreg;                              \
        __builtin_amdgcn_s_setprio(0);                                          \
        lite_barrier();                                                         \
    }

    for (int t = 0; t < LSTM_T; t += 2) {
        STEP(t,     xA0, xA1)
        STEP(t + 1, xB0, xB1)
    }
#undef STEP

    // ---- final h (fp32) -> LDS, then FC + sigmoid ----
    hfin[b][jmine] = hreg;      // pair lanes write same value
    __syncthreads();

    if (tid < BT * LSTM_OUT) {
        int bb = tid >> 3, o = tid & 7;
        float s = b_fc[o];
        #pragma unroll
        for (int j4 = 0; j4 < LSTM_H / 4; ++j4) {
            float4 wv = ld4(W_fc + o * LSTM_H + 4 * j4);
            float4 hv = *reinterpret_cast<const float4*>(&hfin[bb][4 * j4]);
            s = fmaf(wv.x, hv.x, s);
            s = fmaf(wv.y, hv.y, s);
            s = fmaf(wv.z, hv.z, s);
            s = fmaf(wv.w, hv.w, s);
        }
        out[(size_t)(bbase + bb) * LSTM_OUT + o] = sigm2(s * L2E);
    }
}

extern "C" void kernel_launch(void* const* d_in, const int* in_sizes, int n_in,
                              void* d_out, int out_size, void* d_ws, size_t ws_size,
                              hipStream_t stream) {
    const float* x    = (const float*)d_in[0];
    const float* W_ih = (const float*)d_in[1];
    const float* W_hh = (const float*)d_in[2];
    const float* b_ih = (const float*)d_in[3];
    const float* b_hh = (const float*)d_in[4];
    const float* W_fc = (const float*)d_in[5];
    const float* b_fc = (const float*)d_in[6];
    float* out = (float*)d_out;

    lstm_mfma_kernel<<<1024 / BT, 256, 0, stream>>>(
        x, W_ih, W_hh, b_ih, b_hh, W_fc, b_fc, out);
}

// Round 5
// 237.072 us; speedup vs baseline: 1.1989x; 1.1989x over previous
//
#include <hip/hip_runtime.h>
#include <math.h>

// LSTM B=1024,T=512,IN=16,H=64,OUT=8, gates i,f,g,o.
// R17: TIME-BATCHED XW. R16 lesson: issue added between dep points costs
// ~1:1 wall; issue deleted is won. The 4 per-step x-MFMAs (+to_h8+loads)
// existed only because xw was computed per-step with 8x col replication.
// Batched over time (cols = 8 t x 2 b, all real), xw costs 4 MFMAs per 8
// steps (8x fewer). Burst sits in dep-stall windows: MFMAs in the h-read
// latency window, LDS writes in the exp2->rcp stall. xw pairs (fp32
// (f,i)/(g,o), scales+bias folded) live in a dbuf LDS chunk, XOR-swizzled
// by t&7 (reads at b64 4-cyc floor, writes ~floor); each step's pair is
// PRELOADED one step early (chunk written 8 steps back -> race-free), so
// its latency is off-chain. Steady step: 2 h-reads -> 8 h-MFMAs (zero-C
// first half, dependent K-halves -- no R16 split) -> sel+add -> 6-trans
// paired act -> DPP swap -> write -> barrier.
// Kept: DPP lane^8 gate-pairing, symmetric both-halves cs/h (merged
// same-addr writes), scales folded (i,f,o x -L2E; g x +L2E2; cs=L2E2*c),
// setprio over trans tail, dbuf h LDS (HSTRIDE 80), 1 barrier/step,
// 2 blocks/CU.

#define LSTM_T 512
#define LSTM_IN 16
#define LSTM_H 64
#define LSTM_OUT 8
#define BT 2
#define HSTRIDE 80   // halves per batch row; 160B stride = +8 banks
#define XSTR 73      // float2 stride per (t&7, b, half) slot (odd: bank spread)
#define XWSZ 2336    // >= (7*4+3)*73 + 64

#define L2E   1.44269504088896340736f
#define L2E2  2.88539008177792681472f

typedef _Float16 half8  __attribute__((ext_vector_type(8)));
typedef float    floatx4 __attribute__((ext_vector_type(4)));

static __device__ __forceinline__ float fast_rcp(float x) { return __builtin_amdgcn_rcpf(x); }
static __device__ __forceinline__ float fast_exp2(float x) { return __builtin_amdgcn_exp2f(x); }
static __device__ __forceinline__ float sigm2(float p) { return fast_rcp(1.0f + fast_exp2(-p)); }
static __device__ __forceinline__ void pin4(int4& v) {
    asm volatile("" : "+v"(v.x), "+v"(v.y), "+v"(v.z), "+v"(v.w));
}
static __device__ __forceinline__ void pinf4(float4& v) {
    asm volatile("" : "+v"(v.x), "+v"(v.y), "+v"(v.z), "+v"(v.w));
}
static __device__ __forceinline__ void lite_barrier() {
    asm volatile("s_waitcnt lgkmcnt(0)\n\ts_barrier" ::: "memory");
}
static __device__ __forceinline__ unsigned pk2h(float a, float b) {
    return __builtin_bit_cast(unsigned, __builtin_amdgcn_cvt_pkrtz(a, b));
}
static __device__ __forceinline__ half8 to_h8(float4 a, float4 b) {
    uint4 u = make_uint4(pk2h(a.x, a.y), pk2h(a.z, a.w), pk2h(b.x, b.y), pk2h(b.z, b.w));
    return __builtin_bit_cast(half8, u);
}
static __device__ __forceinline__ int4 cvt8h(float4 a, float4 b) {
    return __builtin_bit_cast(int4, to_h8(a, b));
}
static __device__ __forceinline__ float4 ld4(const float* p) {
    return *reinterpret_cast<const float4*>(p);
}
static __device__ __forceinline__ float4 scl4(float4 v, float s) {
    return make_float4(s * v.x, s * v.y, s * v.z, s * v.w);
}
static __device__ __forceinline__ float sel4(floatx4 v, bool r0, bool r1) {
    float lo = r0 ? v[1] : v[0];
    float hi = r0 ? v[3] : v[2];
    return r1 ? hi : lo;
}
// lane^8 exchange via DPP row_ror:8 (full-rate VALU, no LDS pipe)
static __device__ __forceinline__ float dpp8(float v) {
    int r = __builtin_amdgcn_update_dpp(0, __builtin_bit_cast(int, v),
                                        0x128, 0xF, 0xF, false);
    return __builtin_bit_cast(float, r);
}

#define MF(A_, B_, C_) __builtin_amdgcn_mfma_f32_16x16x32_f16( \
        __builtin_bit_cast(half8, A_), (B_), (C_), 0, 0, 0)
#define B4(i) __builtin_bit_cast(floatx4, bias4[i])

__global__ __launch_bounds__(256, 2)
void lstm_mfma_kernel(const float* __restrict__ x,
                      const float* __restrict__ W_ih,
                      const float* __restrict__ W_hh,
                      const float* __restrict__ b_ih,
                      const float* __restrict__ b_hh,
                      const float* __restrict__ W_fc,
                      const float* __restrict__ b_fc,
                      float* __restrict__ out) {
    const int tid   = threadIdx.x;
    const int lane  = tid & 63;
    const int w     = tid >> 6;        // wave -> j-slice [16w, 16w+16)
    const int q     = lane >> 4;       // k-quad / C row group
    const int m     = lane & 15;       // A row-in-tile / B col / C col
    const int b     = m & 1;           // real batch
    const int dt    = m >> 1;          // burst col -> timestep-in-chunk
    const int rho   = (m >> 1) & 3;    // replica id -> C row r to activate
    const bool r0   = (rho & 1) != 0;
    const bool r1   = (rho & 2) != 0;
    const bool h1   = (m & 8) != 0;    // gate-pair half: 0 = f/i, 1 = g/o
    const int h1i   = h1 ? 1 : 0;
    const int jmine = 16 * w + 4 * q + rho;
    const int bbase = blockIdx.x * BT;

    const float a1 = h1 ? 1.0f : 0.0f;
    const float b1 = h1 ? -2.0f : 1.0f;

    __shared__ __align__(16)  float2   xwbuf[2][XWSZ];       // xw chunks, dbuf
    __shared__ __align__(128) _Float16 hbuf[2][BT][HSTRIDE]; // h state, dbuf
    __shared__ __align__(16)  float    hfin[BT][LSTM_H];     // final h for FC

    // ---- weights as pinned fp16 A-fragments, act scales PRE-FOLDED ----
    int4 Ah[4][2], Ax[4];
    float4 bias4[4];
    #pragma unroll
    for (int tt = 0; tt < 4; ++tt) {
        const float sc = (tt == 2) ? L2E2 : -L2E;
        const int gt = tt * 64 + 16 * w + m;
        #pragma unroll
        for (int c = 0; c < 2; ++c) {
            const float* s = W_hh + gt * LSTM_H + 32 * c + 8 * q;
            Ah[tt][c] = cvt8h(scl4(ld4(s), sc), scl4(ld4(s + 4), sc));
            pin4(Ah[tt][c]);
        }
        float4 xa = make_float4(0.f, 0.f, 0.f, 0.f), xb = xa;
        if (q < 2) {
            const float* s = W_ih + gt * LSTM_IN + 8 * q;
            xa = ld4(s); xb = ld4(s + 4);
        }
        Ax[tt] = cvt8h(scl4(xa, sc), scl4(xb, sc));
        pin4(Ax[tt]);
        const int gb = tt * 64 + 16 * w + 4 * q;
        float4 bi = ld4(b_ih + gb), bh = ld4(b_hh + gb);
        bias4[tt] = make_float4(sc * (bi.x + bh.x), sc * (bi.y + bh.y),
                                sc * (bi.z + bh.z), sc * (bi.w + bh.w));
        pinf4(bias4[tt]);
    }

    float4 zc4 = make_float4(0.f, 0.f, 0.f, 0.f);
    pinf4(zc4);
    const floatx4 zc = __builtin_bit_cast(floatx4, zc4);

    // ---- zero hbuf[0] (h_{-1} = 0) ----
    if (tid < 80) reinterpret_cast<int*>(&hbuf[0][0][0])[tid] = 0;

    // ---- burst x pointer: lane covers (b, t0+dt), elems 8q..8q+7 ----
    const float* xpb = x + (size_t)(bbase + b) * LSTM_T * LSTM_IN
                         + (size_t)dt * LSTM_IN + 8 * q;
    float4 Xb0 = make_float4(0.f, 0.f, 0.f, 0.f), Xb1 = Xb0;
    if (q < 2) { Xb0 = ld4(xpb); Xb1 = ld4(xpb + 4); }   // x[0..7]

    // ---- prologue: chunk0 (steps 0..7) -> xwbuf[0] ----
    floatx4 aXi_, aXf_, aXg_, aXo_;
    {
        half8 xfb = to_h8(Xb0, Xb1);
        aXi_ = MF(Ax[0], xfb, B4(0));
        aXf_ = MF(Ax[1], xfb, B4(1));
        aXg_ = MF(Ax[2], xfb, B4(2));
        aXo_ = MF(Ax[3], xfb, B4(3));
        float2* xwch = &xwbuf[0][0];
        #pragma unroll
        for (int r = 0; r < 4; ++r) {
            int jw = (16 * w + 4 * q + r) ^ dt;
            xwch[(dt * 4 + 2 * b + 0) * XSTR + jw] = make_float2(aXf_[r], aXi_[r]);
            xwch[(dt * 4 + 2 * b + 1) * XSTR + jw] = make_float2(aXg_[r], aXo_[r]);
        }
    }
    if (q < 2) {   // x[8..15] for the t=0 burst
        Xb0 = ld4(xpb + 8 * LSTM_IN);
        Xb1 = ld4(xpb + 8 * LSTM_IN + 4);
    }
    __syncthreads();   // hbuf zeros + chunk0 visible

    float2 xwc = xwbuf[0][(2 * b + h1i) * XSTR + jmine];   // t=0 pair
    float cs = 0.0f, hreg = 0.0f;   // cs = L2E2 * c (pre-scaled cell)

// PK = (T_)&1 (hbuf parity), KN = (T_+1)&7, NCB = next step's chunk buf,
// WCB = burst write buf, DOB = compile-time burst flag.
#define STEP_CORE(T_, PK, KN, NCB, WCB, DOB)                                    \
    {                                                                           \
        const _Float16* cur = &hbuf[PK][0][0];                                  \
        _Float16*       nxt = &hbuf[(PK) ^ 1][0][0];                            \
        half8 bh0 = *reinterpret_cast<const half8*>(cur + b * HSTRIDE + 8 * q); \
        half8 bh1 = *reinterpret_cast<const half8*>(cur + b * HSTRIDE + 32 + 8 * q); \
        if (DOB && (T_) + 8 < LSTM_T) {   /* burst MFMAs fill read window */    \
            half8 xfb = to_h8(Xb0, Xb1);                                        \
            aXi_ = MF(Ax[0], xfb, B4(0));                                       \
            aXf_ = MF(Ax[1], xfb, B4(1));                                       \
            aXg_ = MF(Ax[2], xfb, B4(2));                                       \
            aXo_ = MF(Ax[3], xfb, B4(3));                                       \
            if (q < 2 && (T_) + 16 < LSTM_T) {                                  \
                Xb0 = ld4(xpb + (size_t)((T_) + 16) * LSTM_IN);                 \
                Xb1 = ld4(xpb + (size_t)((T_) + 16) * LSTM_IN + 4);             \
            }                                                                   \
        }                                                                       \
        /* preload next step's xw pair (chunk written >=8 steps ago) */         \
        float2 xwn = xwbuf[NCB][((KN) * 4 + 2 * b + h1i) * XSTR                 \
                                + (jmine ^ (KN))];                              \
        floatx4 accf = MF(Ah[1][0], bh0, zc);                                   \
        floatx4 accg = MF(Ah[2][0], bh0, zc);                                   \
        accf = MF(Ah[1][1], bh1, accf);                                         \
        accg = MF(Ah[2][1], bh1, accg);                                         \
        __builtin_amdgcn_s_setprio(1);                                          \
        float uf = sel4(accf, r0, r1);                                          \
        float ug = sel4(accg, r0, r1);                                          \
        float u1 = (h1 ? ug : uf) + xwc.x;                                      \
        float e1 = fast_exp2(u1);                                               \
        floatx4 acci = MF(Ah[0][0], bh0, zc);                                   \
        floatx4 acco = MF(Ah[3][0], bh0, zc);                                   \
        acci = MF(Ah[0][1], bh1, acci);                                         \
        acco = MF(Ah[3][1], bh1, acco);                                         \
        float act1 = fmaf(b1, fast_rcp(1.0f + e1), a1);                         \
        float uii = sel4(acci, r0, r1);                                         \
        float uoo = sel4(acco, r0, r1);                                         \
        float u2 = (h1 ? uoo : uii) + xwc.y;                                    \
        float e2 = fast_exp2(u2);                                               \
        if (DOB && (T_) + 8 < LSTM_T) {   /* burst writes fill e2 stall */      \
            float2* xwch = &xwbuf[WCB][0];                                      \
            _Pragma("unroll")                                                   \
            for (int r = 0; r < 4; ++r) {                                       \
                int jw = (16 * w + 4 * q + r) ^ dt;                             \
                xwch[(dt * 4 + 2 * b + 0) * XSTR + jw] =                        \
                    make_float2(aXf_[r], aXi_[r]);                              \
                xwch[(dt * 4 + 2 * b + 1) * XSTR + jw] =                        \
                    make_float2(aXg_[r], aXo_[r]);                              \
            }                                                                   \
        }                                                                       \
        float act2 = fast_rcp(1.0f + e2);                                       \
        float g_in = dpp8(act1);                                                \
        float o_in = dpp8(act2);                                                \
        float fsel = h1 ? g_in : act1;   /* sigma(f) */                         \
        float isel = h1 ? o_in : act2;   /* sigma(i) */                         \
        float gsel = h1 ? act1 : g_in;   /* tanh(g)  */                         \
        float osel = h1 ? act2 : o_in;   /* sigma(o) */                         \
        cs = fmaf(fsel, cs, (L2E2 * isel) * gsel);                              \
        float th = fmaf(-2.0f, fast_rcp(1.0f + fast_exp2(cs)), 1.0f);           \
        hreg = osel * th;                                                       \
        nxt[b * HSTRIDE + jmine] = (_Float16)hreg;                              \
        __builtin_amdgcn_s_setprio(0);                                          \
        lite_barrier();                                                         \
        xwc = xwn;                                                              \
    }

    for (int t8 = 0; t8 < LSTM_T; t8 += 8) {
        const int cb = (t8 >> 3) & 1;
        const int wb = cb ^ 1;
        STEP_CORE(t8,     0, 1, cb, wb, 1)
        STEP_CORE(t8 + 1, 1, 2, cb, 0, 0)
        STEP_CORE(t8 + 2, 0, 3, cb, 0, 0)
        STEP_CORE(t8 + 3, 1, 4, cb, 0, 0)
        STEP_CORE(t8 + 4, 0, 5, cb, 0, 0)
        STEP_CORE(t8 + 5, 1, 6, cb, 0, 0)
        STEP_CORE(t8 + 6, 0, 7, cb, 0, 0)
        STEP_CORE(t8 + 7, 1, 0, wb, 0, 0)
    }
#undef STEP_CORE

    // ---- final h (fp32) -> LDS, then FC + sigmoid ----
    hfin[b][jmine] = hreg;      // pair lanes write same value
    __syncthreads();

    if (tid < BT * LSTM_OUT) {
        int bb = tid >> 3, o = tid & 7;
        float s = b_fc[o];
        #pragma unroll
        for (int j4 = 0; j4 < LSTM_H / 4; ++j4) {
            float4 wv = ld4(W_fc + o * LSTM_H + 4 * j4);
            float4 hv = *reinterpret_cast<const float4*>(&hfin[bb][4 * j4]);
            s = fmaf(wv.x, hv.x, s);
            s = fmaf(wv.y, hv.y, s);
            s = fmaf(wv.z, hv.z, s);
            s = fmaf(wv.w, hv.w, s);
        }
        out[(size_t)(bbase + bb) * LSTM_OUT + o] = sigm2(s * L2E);
    }
}

extern "C" void kernel_launch(void* const* d_in, const int* in_sizes, int n_in,
                              void* d_out, int out_size, void* d_ws, size_t ws_size,
                              hipStream_t stream) {
    const float* x    = (const float*)d_in[0];
    const float* W_ih = (const float*)d_in[1];
    const float* W_hh = (const float*)d_in[2];
    const float* b_ih = (const float*)d_in[3];
    const float* b_hh = (const float*)d_in[4];
    const float* W_fc = (const float*)d_in[5];
    const float* b_fc = (const float*)d_in[6];
    float* out = (float*)d_out;

    lstm_mfma_kernel<<<1024 / BT, 256, 0, stream>>>(
        x, W_ih, W_hh, b_ih, b_hh, W_fc, b_fc, out);
}

// Round 6
// 234.356 us; speedup vs baseline: 1.2128x; 1.0116x over previous
//
#include <hip/hip_runtime.h>
#include <math.h>

// LSTM B=1024,T=512,IN=16,H=64,OUT=8, gates i,f,g,o.
// R18: SPREAD BURST + BREADTH-FIRST MFMA. R17 (905cyc/step) matched its
// prediction: wall = per-wave in-order stream. Remaining holes: (1) the
// xw burst (4 MFMA + 8 writes + 2 gloads) lumped into 1 of 8 steps, so
// 7/8 steps have a naked ~100cyc ds_read->MFMA stall window; (2) the
// dependent K-half MFMA pairs stall ~20-40cyc twice/step.
//   1) burst spread 1 micro-op/step into the read window: K0 to_h8+MF_i,
//      K1..K3 MF_f/g/o, K4..K7 two LDS writes each (K6/K7 + global x
//      load). aX regs live across the chunk (+16 VGPR, fine).
//   2) h-MFMAs breadth-first f0,g0,i0,o0,f1,g1 -> sel/e1 -> i1,o1 ->
//      sel/e2: all dep gaps >= 3 MFMAs (~58cyc) -> no dep stall; i1/o1
//      issue under e1 latency.
// Kept from R17: time-batched xw in dbuf XOR-swizzled LDS chunks (pairs
// preloaded 1 step early), DPP lane^8 gate-pairing (6 trans/step),
// symmetric both-halves cs/h (merged same-addr writes), scales folded
// (i,f,o x -L2E; g x +L2E2; cs = L2E2*c), setprio over trans tail,
// dbuf h LDS (HSTRIDE 80), 1 lite barrier/step, 2 blocks/CU.

#define LSTM_T 512
#define LSTM_IN 16
#define LSTM_H 64
#define LSTM_OUT 8
#define BT 2
#define HSTRIDE 80   // halves per batch row; 160B stride = +8 banks
#define XSTR 73      // float2 stride per (t&7, b, half) slot (odd: bank spread)
#define XWSZ 2336    // >= (7*4+3)*73 + 64

#define L2E   1.44269504088896340736f
#define L2E2  2.88539008177792681472f

typedef _Float16 half8  __attribute__((ext_vector_type(8)));
typedef float    floatx4 __attribute__((ext_vector_type(4)));

static __device__ __forceinline__ float fast_rcp(float x) { return __builtin_amdgcn_rcpf(x); }
static __device__ __forceinline__ float fast_exp2(float x) { return __builtin_amdgcn_exp2f(x); }
static __device__ __forceinline__ float sigm2(float p) { return fast_rcp(1.0f + fast_exp2(-p)); }
static __device__ __forceinline__ void pin4(int4& v) {
    asm volatile("" : "+v"(v.x), "+v"(v.y), "+v"(v.z), "+v"(v.w));
}
static __device__ __forceinline__ void pinf4(float4& v) {
    asm volatile("" : "+v"(v.x), "+v"(v.y), "+v"(v.z), "+v"(v.w));
}
static __device__ __forceinline__ void lite_barrier() {
    asm volatile("s_waitcnt lgkmcnt(0)\n\ts_barrier" ::: "memory");
}
static __device__ __forceinline__ unsigned pk2h(float a, float b) {
    return __builtin_bit_cast(unsigned, __builtin_amdgcn_cvt_pkrtz(a, b));
}
static __device__ __forceinline__ half8 to_h8(float4 a, float4 b) {
    uint4 u = make_uint4(pk2h(a.x, a.y), pk2h(a.z, a.w), pk2h(b.x, b.y), pk2h(b.z, b.w));
    return __builtin_bit_cast(half8, u);
}
static __device__ __forceinline__ int4 cvt8h(float4 a, float4 b) {
    return __builtin_bit_cast(int4, to_h8(a, b));
}
static __device__ __forceinline__ float4 ld4(const float* p) {
    return *reinterpret_cast<const float4*>(p);
}
static __device__ __forceinline__ float4 scl4(float4 v, float s) {
    return make_float4(s * v.x, s * v.y, s * v.z, s * v.w);
}
static __device__ __forceinline__ float sel4(floatx4 v, bool r0, bool r1) {
    float lo = r0 ? v[1] : v[0];
    float hi = r0 ? v[3] : v[2];
    return r1 ? hi : lo;
}
// lane^8 exchange via DPP row_ror:8 (full-rate VALU, no LDS pipe)
static __device__ __forceinline__ float dpp8(float v) {
    int r = __builtin_amdgcn_update_dpp(0, __builtin_bit_cast(int, v),
                                        0x128, 0xF, 0xF, false);
    return __builtin_bit_cast(float, r);
}

#define MF(A_, B_, C_) __builtin_amdgcn_mfma_f32_16x16x32_f16( \
        __builtin_bit_cast(half8, A_), (B_), (C_), 0, 0, 0)
#define B4(i) __builtin_bit_cast(floatx4, bias4[i])

__global__ __launch_bounds__(256, 2)
void lstm_mfma_kernel(const float* __restrict__ x,
                      const float* __restrict__ W_ih,
                      const float* __restrict__ W_hh,
                      const float* __restrict__ b_ih,
                      const float* __restrict__ b_hh,
                      const float* __restrict__ W_fc,
                      const float* __restrict__ b_fc,
                      float* __restrict__ out) {
    const int tid   = threadIdx.x;
    const int lane  = tid & 63;
    const int w     = tid >> 6;        // wave -> j-slice [16w, 16w+16)
    const int q     = lane >> 4;       // k-quad / C row group
    const int m     = lane & 15;       // A row-in-tile / B col / C col
    const int b     = m & 1;           // real batch
    const int dt    = m >> 1;          // burst col -> timestep-in-chunk
    const int rho   = (m >> 1) & 3;    // replica id -> C row r to activate
    const bool r0   = (rho & 1) != 0;
    const bool r1   = (rho & 2) != 0;
    const bool h1   = (m & 8) != 0;    // gate-pair half: 0 = f/i, 1 = g/o
    const int h1i   = h1 ? 1 : 0;
    const int jmine = 16 * w + 4 * q + rho;
    const int bbase = blockIdx.x * BT;

    const float a1 = h1 ? 1.0f : 0.0f;
    const float b1 = h1 ? -2.0f : 1.0f;

    __shared__ __align__(16)  float2   xwbuf[2][XWSZ];       // xw chunks, dbuf
    __shared__ __align__(128) _Float16 hbuf[2][BT][HSTRIDE]; // h state, dbuf
    __shared__ __align__(16)  float    hfin[BT][LSTM_H];     // final h for FC

    // ---- weights as pinned fp16 A-fragments, act scales PRE-FOLDED ----
    int4 Ah[4][2], Ax[4];
    float4 bias4[4];
    #pragma unroll
    for (int tt = 0; tt < 4; ++tt) {
        const float sc = (tt == 2) ? L2E2 : -L2E;
        const int gt = tt * 64 + 16 * w + m;
        #pragma unroll
        for (int c = 0; c < 2; ++c) {
            const float* s = W_hh + gt * LSTM_H + 32 * c + 8 * q;
            Ah[tt][c] = cvt8h(scl4(ld4(s), sc), scl4(ld4(s + 4), sc));
            pin4(Ah[tt][c]);
        }
        float4 xa = make_float4(0.f, 0.f, 0.f, 0.f), xb = xa;
        if (q < 2) {
            const float* s = W_ih + gt * LSTM_IN + 8 * q;
            xa = ld4(s); xb = ld4(s + 4);
        }
        Ax[tt] = cvt8h(scl4(xa, sc), scl4(xb, sc));
        pin4(Ax[tt]);
        const int gb = tt * 64 + 16 * w + 4 * q;
        float4 bi = ld4(b_ih + gb), bh = ld4(b_hh + gb);
        bias4[tt] = make_float4(sc * (bi.x + bh.x), sc * (bi.y + bh.y),
                                sc * (bi.z + bh.z), sc * (bi.w + bh.w));
        pinf4(bias4[tt]);
    }

    float4 zc4 = make_float4(0.f, 0.f, 0.f, 0.f);
    pinf4(zc4);
    const floatx4 zc = __builtin_bit_cast(floatx4, zc4);

    // ---- zero hbuf[0] (h_{-1} = 0) ----
    if (tid < 80) reinterpret_cast<int*>(&hbuf[0][0][0])[tid] = 0;

    // ---- burst x pointer: lane covers (b, t0+dt), elems 8q..8q+7 ----
    const float* xpb = x + (size_t)(bbase + b) * LSTM_T * LSTM_IN
                         + (size_t)dt * LSTM_IN + 8 * q;
    float4 Xb0 = make_float4(0.f, 0.f, 0.f, 0.f), Xb1 = Xb0;
    if (q < 2) { Xb0 = ld4(xpb); Xb1 = ld4(xpb + 4); }   // chunk 0

    // ---- prologue: chunk0 (steps 0..7) -> xwbuf[0] ----
    floatx4 aXi_, aXf_, aXg_, aXo_;
    half8 xfb;
    {
        half8 x0 = to_h8(Xb0, Xb1);
        aXi_ = MF(Ax[0], x0, B4(0));
        aXf_ = MF(Ax[1], x0, B4(1));
        aXg_ = MF(Ax[2], x0, B4(2));
        aXo_ = MF(Ax[3], x0, B4(3));
        float2* xwch = &xwbuf[0][0];
        #pragma unroll
        for (int r = 0; r < 4; ++r) {
            int jw = (16 * w + 4 * q + r) ^ dt;
            xwch[(dt * 4 + 2 * b + 0) * XSTR + jw] = make_float2(aXf_[r], aXi_[r]);
            xwch[(dt * 4 + 2 * b + 1) * XSTR + jw] = make_float2(aXg_[r], aXo_[r]);
        }
    }
    if (q < 2) {   // x for chunk 1 (steps 8..15)
        Xb0 = ld4(xpb + 8 * LSTM_IN);
        Xb1 = ld4(xpb + 8 * LSTM_IN + 4);
    }
    __syncthreads();   // hbuf zeros + chunk0 visible

    float2 xwc = xwbuf[0][(2 * b + h1i) * XSTR + jmine];   // t=0 pair
    float cs = 0.0f, hreg = 0.0f;   // cs = L2E2 * c (pre-scaled cell)

// PK = hbuf parity, KN = next step's k (t&7), NCB = next step's chunk buf.
// __VA_ARGS__ = the spread-burst micro-op for this step (sits in the
// ds_read latency window).
#define STEP_CORE(T_, PK, KN, NCB, ...)                                         \
    {                                                                           \
        const _Float16* cur = &hbuf[PK][0][0];                                  \
        _Float16*       nxt = &hbuf[(PK) ^ 1][0][0];                            \
        half8 bh0 = *reinterpret_cast<const half8*>(cur + b * HSTRIDE + 8 * q); \
        half8 bh1 = *reinterpret_cast<const half8*>(cur + b * HSTRIDE + 32 + 8 * q); \
        __VA_ARGS__                                                             \
        /* preload next step's xw pair (chunk written >=8 steps ago) */         \
        float2 xwn = xwbuf[NCB][((KN) * 4 + 2 * b + h1i) * XSTR                 \
                                + (jmine ^ (KN))];                              \
        /* breadth-first h-MFMAs: all dep gaps >= 3 (no stall) */               \
        floatx4 accf = MF(Ah[1][0], bh0, zc);                                   \
        floatx4 accg = MF(Ah[2][0], bh0, zc);                                   \
        floatx4 acci = MF(Ah[0][0], bh0, zc);                                   \
        floatx4 acco = MF(Ah[3][0], bh0, zc);                                   \
        accf = MF(Ah[1][1], bh1, accf);                                         \
        accg = MF(Ah[2][1], bh1, accg);                                         \
        __builtin_amdgcn_s_setprio(1);                                          \
        float uf = sel4(accf, r0, r1);                                          \
        float ug = sel4(accg, r0, r1);                                          \
        float u1 = (h1 ? ug : uf) + xwc.x;                                      \
        float e1 = fast_exp2(u1);                                               \
        acci = MF(Ah[0][1], bh1, acci);                                         \
        acco = MF(Ah[3][1], bh1, acco);                                         \
        float act1 = fmaf(b1, fast_rcp(1.0f + e1), a1);                         \
        float uii = sel4(acci, r0, r1);                                         \
        float uoo = sel4(acco, r0, r1);                                         \
        float u2 = (h1 ? uoo : uii) + xwc.y;                                    \
        float e2 = fast_exp2(u2);                                               \
        float act2 = fast_rcp(1.0f + e2);                                       \
        float g_in = dpp8(act1);                                                \
        float o_in = dpp8(act2);                                                \
        float fsel = h1 ? g_in : act1;   /* sigma(f) */                         \
        float isel = h1 ? o_in : act2;   /* sigma(i) */                         \
        float gsel = h1 ? act1 : g_in;   /* tanh(g)  */                         \
        float osel = h1 ? act2 : o_in;   /* sigma(o) */                         \
        cs = fmaf(fsel, cs, (L2E2 * isel) * gsel);                              \
        float th = fmaf(-2.0f, fast_rcp(1.0f + fast_exp2(cs)), 1.0f);           \
        hreg = osel * th;                                                       \
        nxt[b * HSTRIDE + jmine] = (_Float16)hreg;                              \
        __builtin_amdgcn_s_setprio(0);                                          \
        lite_barrier();                                                         \
        xwc = xwn;                                                              \
    }

// burst LDS write of pair PR (0=(f,i),1=(g,o)), rows R_ and R_+1, into buf WB
#define BWR(WB, PR, R_)                                                         \
    {                                                                           \
        float2* xwch = &xwbuf[WB][0];                                           \
        int jw0 = (16 * w + 4 * q + (R_)) ^ dt;                                 \
        int jw1 = (16 * w + 4 * q + (R_) + 1) ^ dt;                             \
        xwch[(dt * 4 + 2 * b + (PR)) * XSTR + jw0] = (PR)                       \
            ? make_float2(aXg_[(R_)], aXo_[(R_)])                               \
            : make_float2(aXf_[(R_)], aXi_[(R_)]);                              \
        xwch[(dt * 4 + 2 * b + (PR)) * XSTR + jw1] = (PR)                       \
            ? make_float2(aXg_[(R_) + 1], aXo_[(R_) + 1])                       \
            : make_float2(aXf_[(R_) + 1], aXi_[(R_) + 1]);                      \
    }

    for (int t8 = 0; t8 < LSTM_T; t8 += 8) {
        const int cb = (t8 >> 3) & 1;
        const int wb = cb ^ 1;
        const bool dob = t8 < LSTM_T - 8;    // produce next chunk?
        const bool dox = t8 < LSTM_T - 16;   // load chunk-after-next x?
        STEP_CORE(t8 + 0, 0, 1, cb,
            if (dob) { xfb = to_h8(Xb0, Xb1); aXi_ = MF(Ax[0], xfb, B4(0)); })
        STEP_CORE(t8 + 1, 1, 2, cb,
            if (dob) { aXf_ = MF(Ax[1], xfb, B4(1)); })
        STEP_CORE(t8 + 2, 0, 3, cb,
            if (dob) { aXg_ = MF(Ax[2], xfb, B4(2)); })
        STEP_CORE(t8 + 3, 1, 4, cb,
            if (dob) { aXo_ = MF(Ax[3], xfb, B4(3)); })
        STEP_CORE(t8 + 4, 0, 5, cb,
            if (dob) { BWR(wb, 0, 0) })
        STEP_CORE(t8 + 5, 1, 6, cb,
            if (dob) { BWR(wb, 0, 2) })
        STEP_CORE(t8 + 6, 0, 7, cb,
            if (dob) { BWR(wb, 1, 0) }
            if (q < 2 && dox) { Xb0 = ld4(xpb + (size_t)(t8 + 16) * LSTM_IN); })
        STEP_CORE(t8 + 7, 1, 0, wb,
            if (dob) { BWR(wb, 1, 2) }
            if (q < 2 && dox) { Xb1 = ld4(xpb + (size_t)(t8 + 16) * LSTM_IN + 4); })
    }
#undef STEP_CORE
#undef BWR

    // ---- final h (fp32) -> LDS, then FC + sigmoid ----
    hfin[b][jmine] = hreg;      // pair lanes write same value
    __syncthreads();

    if (tid < BT * LSTM_OUT) {
        int bb = tid >> 3, o = tid & 7;
        float s = b_fc[o];
        #pragma unroll
        for (int j4 = 0; j4 < LSTM_H / 4; ++j4) {
            float4 wv = ld4(W_fc + o * LSTM_H + 4 * j4);
            float4 hv = *reinterpret_cast<const float4*>(&hfin[bb][4 * j4]);
            s = fmaf(wv.x, hv.x, s);
            s = fmaf(wv.y, hv.y, s);
            s = fmaf(wv.z, hv.z, s);
            s = fmaf(wv.w, hv.w, s);
        }
        out[(size_t)(bbase + bb) * LSTM_OUT + o] = sigm2(s * L2E);
    }
}

extern "C" void kernel_launch(void* const* d_in, const int* in_sizes, int n_in,
                              void* d_out, int out_size, void* d_ws, size_t ws_size,
                              hipStream_t stream) {
    const float* x    = (const float*)d_in[0];
    const float* W_ih = (const float*)d_in[1];
    const float* W_hh = (const float*)d_in[2];
    const float* b_ih = (const float*)d_in[3];
    const float* b_hh = (const float*)d_in[4];
    const float* W_fc = (const float*)d_in[5];
    const float* b_fc = (const float*)d_in[6];
    float* out = (float*)d_out;

    lstm_mfma_kernel<<<1024 / BT, 256, 0, stream>>>(
        x, W_ih, W_hh, b_ih, b_hh, W_fc, b_fc, out);
}

// Round 7
// 226.467 us; speedup vs baseline: 1.2551x; 1.0348x over previous
//
#include <hip/hip_runtime.h>
#include <math.h>

// LSTM B=1024,T=512,IN=16,H=64,OUT=8, gates i,f,g,o.
// R19: ASYMMETRIC ROLES. R18 counters: VALU 537 + MFMA 296 = 833 of 895
// cyc/SIMD/step -> 93% issue-saturated; latency hidden by sibling wave;
// only instruction deletion moves the wall. Deleted: the symmetric-halves
// role-selects. half1's cs/h were never semantically needed (it exists to
// compute tanh(g)/sigma(o) and DPP-ship them), so:
//   1) canonical roles on half0: cs = fmaf(act1, cs, (K*act2)*g_in) with
//      ZERO cndmasks (act1=sigma(f), act2=sigma(i), g_in/o_in via dpp8).
//      half1 computes bounded garbage cs (saturates finitely, no NaN),
//      never read.
//   2) h-write exec-masked to half0 (wr = m<8); garbage never hits hbuf.
//   3) tail: h = o*(1-2r) = fmaf(-2o, r, o), -2o computed under rcp
//      latency (one mul off the chain).
// Kept from R18: spread xw burst (1 micro-op/step in the read window),
// breadth-first h-MFMAs (dep gaps >= 3), time-batched xw in dbuf
// XOR-swizzled LDS chunks (pairs preloaded 1 step early), DPP lane^8
// gate-pairing (6 trans/step), scales folded (i,f,o x -L2E; g x +L2E2;
// cs = L2E2*c), setprio over trans tail, dbuf h LDS (HSTRIDE 80),
// 1 lite barrier/step, 2 blocks/CU.

#define LSTM_T 512
#define LSTM_IN 16
#define LSTM_H 64
#define LSTM_OUT 8
#define BT 2
#define HSTRIDE 80   // halves per batch row; 160B stride = +8 banks
#define XSTR 73      // float2 stride per (t&7, b, half) slot (odd: bank spread)
#define XWSZ 2336    // >= (7*4+3)*73 + 64

#define L2E   1.44269504088896340736f
#define L2E2  2.88539008177792681472f

typedef _Float16 half8  __attribute__((ext_vector_type(8)));
typedef float    floatx4 __attribute__((ext_vector_type(4)));

static __device__ __forceinline__ float fast_rcp(float x) { return __builtin_amdgcn_rcpf(x); }
static __device__ __forceinline__ float fast_exp2(float x) { return __builtin_amdgcn_exp2f(x); }
static __device__ __forceinline__ float sigm2(float p) { return fast_rcp(1.0f + fast_exp2(-p)); }
static __device__ __forceinline__ void pin4(int4& v) {
    asm volatile("" : "+v"(v.x), "+v"(v.y), "+v"(v.z), "+v"(v.w));
}
static __device__ __forceinline__ void pinf4(float4& v) {
    asm volatile("" : "+v"(v.x), "+v"(v.y), "+v"(v.z), "+v"(v.w));
}
static __device__ __forceinline__ void lite_barrier() {
    asm volatile("s_waitcnt lgkmcnt(0)\n\ts_barrier" ::: "memory");
}
static __device__ __forceinline__ unsigned pk2h(float a, float b) {
    return __builtin_bit_cast(unsigned, __builtin_amdgcn_cvt_pkrtz(a, b));
}
static __device__ __forceinline__ half8 to_h8(float4 a, float4 b) {
    uint4 u = make_uint4(pk2h(a.x, a.y), pk2h(a.z, a.w), pk2h(b.x, b.y), pk2h(b.z, b.w));
    return __builtin_bit_cast(half8, u);
}
static __device__ __forceinline__ int4 cvt8h(float4 a, float4 b) {
    return __builtin_bit_cast(int4, to_h8(a, b));
}
static __device__ __forceinline__ float4 ld4(const float* p) {
    return *reinterpret_cast<const float4*>(p);
}
static __device__ __forceinline__ float4 scl4(float4 v, float s) {
    return make_float4(s * v.x, s * v.y, s * v.z, s * v.w);
}
static __device__ __forceinline__ float sel4(floatx4 v, bool r0, bool r1) {
    float lo = r0 ? v[1] : v[0];
    float hi = r0 ? v[3] : v[2];
    return r1 ? hi : lo;
}
// lane^8 exchange via DPP row_ror:8 (full-rate VALU, no LDS pipe)
static __device__ __forceinline__ float dpp8(float v) {
    int r = __builtin_amdgcn_update_dpp(0, __builtin_bit_cast(int, v),
                                        0x128, 0xF, 0xF, false);
    return __builtin_bit_cast(float, r);
}

#define MF(A_, B_, C_) __builtin_amdgcn_mfma_f32_16x16x32_f16( \
        __builtin_bit_cast(half8, A_), (B_), (C_), 0, 0, 0)
#define B4(i) __builtin_bit_cast(floatx4, bias4[i])

__global__ __launch_bounds__(256, 2)
void lstm_mfma_kernel(const float* __restrict__ x,
                      const float* __restrict__ W_ih,
                      const float* __restrict__ W_hh,
                      const float* __restrict__ b_ih,
                      const float* __restrict__ b_hh,
                      const float* __restrict__ W_fc,
                      const float* __restrict__ b_fc,
                      float* __restrict__ out) {
    const int tid   = threadIdx.x;
    const int lane  = tid & 63;
    const int w     = tid >> 6;        // wave -> j-slice [16w, 16w+16)
    const int q     = lane >> 4;       // k-quad / C row group
    const int m     = lane & 15;       // A row-in-tile / B col / C col
    const int b     = m & 1;           // real batch
    const int dt    = m >> 1;          // burst col -> timestep-in-chunk
    const int rho   = (m >> 1) & 3;    // replica id -> C row r to activate
    const bool r0   = (rho & 1) != 0;
    const bool r1   = (rho & 2) != 0;
    const bool h1   = (m & 8) != 0;    // gate-pair half: 0 = f/i, 1 = g/o
    const int h1i   = h1 ? 1 : 0;
    const bool wr   = (m < 8);         // half0 holds the valid c/h state
    const int jmine = 16 * w + 4 * q + rho;
    const int bbase = blockIdx.x * BT;

    const float a1 = h1 ? 1.0f : 0.0f;
    const float b1 = h1 ? -2.0f : 1.0f;

    __shared__ __align__(16)  float2   xwbuf[2][XWSZ];       // xw chunks, dbuf
    __shared__ __align__(128) _Float16 hbuf[2][BT][HSTRIDE]; // h state, dbuf
    __shared__ __align__(16)  float    hfin[BT][LSTM_H];     // final h for FC

    // ---- weights as pinned fp16 A-fragments, act scales PRE-FOLDED ----
    int4 Ah[4][2], Ax[4];
    float4 bias4[4];
    #pragma unroll
    for (int tt = 0; tt < 4; ++tt) {
        const float sc = (tt == 2) ? L2E2 : -L2E;
        const int gt = tt * 64 + 16 * w + m;
        #pragma unroll
        for (int c = 0; c < 2; ++c) {
            const float* s = W_hh + gt * LSTM_H + 32 * c + 8 * q;
            Ah[tt][c] = cvt8h(scl4(ld4(s), sc), scl4(ld4(s + 4), sc));
            pin4(Ah[tt][c]);
        }
        float4 xa = make_float4(0.f, 0.f, 0.f, 0.f), xb = xa;
        if (q < 2) {
            const float* s = W_ih + gt * LSTM_IN + 8 * q;
            xa = ld4(s); xb = ld4(s + 4);
        }
        Ax[tt] = cvt8h(scl4(xa, sc), scl4(xb, sc));
        pin4(Ax[tt]);
        const int gb = tt * 64 + 16 * w + 4 * q;
        float4 bi = ld4(b_ih + gb), bh = ld4(b_hh + gb);
        bias4[tt] = make_float4(sc * (bi.x + bh.x), sc * (bi.y + bh.y),
                                sc * (bi.z + bh.z), sc * (bi.w + bh.w));
        pinf4(bias4[tt]);
    }

    float4 zc4 = make_float4(0.f, 0.f, 0.f, 0.f);
    pinf4(zc4);
    const floatx4 zc = __builtin_bit_cast(floatx4, zc4);

    // ---- zero hbuf[0] (h_{-1} = 0) ----
    if (tid < 80) reinterpret_cast<int*>(&hbuf[0][0][0])[tid] = 0;

    // ---- burst x pointer: lane covers (b, t0+dt), elems 8q..8q+7 ----
    const float* xpb = x + (size_t)(bbase + b) * LSTM_T * LSTM_IN
                         + (size_t)dt * LSTM_IN + 8 * q;
    float4 Xb0 = make_float4(0.f, 0.f, 0.f, 0.f), Xb1 = Xb0;
    if (q < 2) { Xb0 = ld4(xpb); Xb1 = ld4(xpb + 4); }   // chunk 0

    // ---- prologue: chunk0 (steps 0..7) -> xwbuf[0] ----
    floatx4 aXi_, aXf_, aXg_, aXo_;
    half8 xfb;
    {
        half8 x0 = to_h8(Xb0, Xb1);
        aXi_ = MF(Ax[0], x0, B4(0));
        aXf_ = MF(Ax[1], x0, B4(1));
        aXg_ = MF(Ax[2], x0, B4(2));
        aXo_ = MF(Ax[3], x0, B4(3));
        float2* xwch = &xwbuf[0][0];
        #pragma unroll
        for (int r = 0; r < 4; ++r) {
            int jw = (16 * w + 4 * q + r) ^ dt;
            xwch[(dt * 4 + 2 * b + 0) * XSTR + jw] = make_float2(aXf_[r], aXi_[r]);
            xwch[(dt * 4 + 2 * b + 1) * XSTR + jw] = make_float2(aXg_[r], aXo_[r]);
        }
    }
    if (q < 2) {   // x for chunk 1 (steps 8..15)
        Xb0 = ld4(xpb + 8 * LSTM_IN);
        Xb1 = ld4(xpb + 8 * LSTM_IN + 4);
    }
    __syncthreads();   // hbuf zeros + chunk0 visible

    float2 xwc = xwbuf[0][(2 * b + h1i) * XSTR + jmine];   // t=0 pair
    float cs = 0.0f, hreg = 0.0f;   // cs = L2E2 * c (pre-scaled, half0 valid)

// PK = hbuf parity, KN = next step's k (t&7), NCB = next step's chunk buf.
// __VA_ARGS__ = the spread-burst micro-op for this step (sits in the
// ds_read latency window).
#define STEP_CORE(T_, PK, KN, NCB, ...)                                         \
    {                                                                           \
        const _Float16* cur = &hbuf[PK][0][0];                                  \
        _Float16*       nxt = &hbuf[(PK) ^ 1][0][0];                            \
        half8 bh0 = *reinterpret_cast<const half8*>(cur + b * HSTRIDE + 8 * q); \
        half8 bh1 = *reinterpret_cast<const half8*>(cur + b * HSTRIDE + 32 + 8 * q); \
        __VA_ARGS__                                                             \
        /* preload next step's xw pair (chunk written >=8 steps ago) */         \
        float2 xwn = xwbuf[NCB][((KN) * 4 + 2 * b + h1i) * XSTR                 \
                                + (jmine ^ (KN))];                              \
        /* breadth-first h-MFMAs: all dep gaps >= 3 (no stall) */               \
        floatx4 accf = MF(Ah[1][0], bh0, zc);                                   \
        floatx4 accg = MF(Ah[2][0], bh0, zc);                                   \
        floatx4 acci = MF(Ah[0][0], bh0, zc);                                   \
        floatx4 acco = MF(Ah[3][0], bh0, zc);                                   \
        accf = MF(Ah[1][1], bh1, accf);                                         \
        accg = MF(Ah[2][1], bh1, accg);                                         \
        __builtin_amdgcn_s_setprio(1);                                          \
        float uf = sel4(accf, r0, r1);                                          \
        float ug = sel4(accg, r0, r1);                                          \
        float u1 = (h1 ? ug : uf) + xwc.x;                                      \
        float e1 = fast_exp2(u1);                                               \
        acci = MF(Ah[0][1], bh1, acci);                                         \
        acco = MF(Ah[3][1], bh1, acco);                                         \
        /* act1: sigma(f) on half0 (b1=1,a1=0 -> identity), tanh(g) on h1 */    \
        float act1 = fmaf(b1, fast_rcp(1.0f + e1), a1);                         \
        float uii = sel4(acci, r0, r1);                                         \
        float uoo = sel4(acco, r0, r1);                                         \
        float u2 = (h1 ? uoo : uii) + xwc.y;                                    \
        float e2 = fast_exp2(u2);                                               \
        float act2 = fast_rcp(1.0f + e2);    /* sigma(i) on h0, sigma(o) h1 */  \
        float g_in = dpp8(act1);             /* h0 receives tanh(g) */          \
        float o_in = dpp8(act2);             /* h0 receives sigma(o) */         \
        float Ki   = L2E2 * act2;            /* K*sigma(i), off-chain */        \
        /* canonical on half0, bounded garbage on half1 (never read) */         \
        cs = fmaf(act1, cs, Ki * g_in);                                         \
        float E  = fast_exp2(cs);                                               \
        float r_ = fast_rcp(1.0f + E);                                          \
        float n2o = -2.0f * o_in;            /* under rcp latency */            \
        hreg = fmaf(n2o, r_, o_in);          /* o * tanh(cs) */                 \
        if (wr) nxt[b * HSTRIDE + jmine] = (_Float16)hreg;                      \
        __builtin_amdgcn_s_setprio(0);                                          \
        lite_barrier();                                                         \
        xwc = xwn;                                                              \
    }

// burst LDS write of pair PR (0=(f,i),1=(g,o)), rows R_ and R_+1, into buf WB
#define BWR(WB, PR, R_)                                                         \
    {                                                                           \
        float2* xwch = &xwbuf[WB][0];                                           \
        int jw0 = (16 * w + 4 * q + (R_)) ^ dt;                                 \
        int jw1 = (16 * w + 4 * q + (R_) + 1) ^ dt;                             \
        xwch[(dt * 4 + 2 * b + (PR)) * XSTR + jw0] = (PR)                       \
            ? make_float2(aXg_[(R_)], aXo_[(R_)])                               \
            : make_float2(aXf_[(R_)], aXi_[(R_)]);                              \
        xwch[(dt * 4 + 2 * b + (PR)) * XSTR + jw1] = (PR)                       \
            ? make_float2(aXg_[(R_) + 1], aXo_[(R_) + 1])                       \
            : make_float2(aXf_[(R_) + 1], aXi_[(R_) + 1]);                      \
    }

    for (int t8 = 0; t8 < LSTM_T; t8 += 8) {
        const int cb = (t8 >> 3) & 1;
        const int wb = cb ^ 1;
        const bool dob = t8 < LSTM_T - 8;    // produce next chunk?
        const bool dox = t8 < LSTM_T - 16;   // load chunk-after-next x?
        STEP_CORE(t8 + 0, 0, 1, cb,
            if (dob) { xfb = to_h8(Xb0, Xb1); aXi_ = MF(Ax[0], xfb, B4(0)); })
        STEP_CORE(t8 + 1, 1, 2, cb,
            if (dob) { aXf_ = MF(Ax[1], xfb, B4(1)); })
        STEP_CORE(t8 + 2, 0, 3, cb,
            if (dob) { aXg_ = MF(Ax[2], xfb, B4(2)); })
        STEP_CORE(t8 + 3, 1, 4, cb,
            if (dob) { aXo_ = MF(Ax[3], xfb, B4(3)); })
        STEP_CORE(t8 + 4, 0, 5, cb,
            if (dob) { BWR(wb, 0, 0) })
        STEP_CORE(t8 + 5, 1, 6, cb,
            if (dob) { BWR(wb, 0, 2) })
        STEP_CORE(t8 + 6, 0, 7, cb,
            if (dob) { BWR(wb, 1, 0) }
            if (q < 2 && dox) { Xb0 = ld4(xpb + (size_t)(t8 + 16) * LSTM_IN); })
        STEP_CORE(t8 + 7, 1, 0, wb,
            if (dob) { BWR(wb, 1, 2) }
            if (q < 2 && dox) { Xb1 = ld4(xpb + (size_t)(t8 + 16) * LSTM_IN + 4); })
    }
#undef STEP_CORE
#undef BWR

    // ---- final h (fp32) -> LDS, then FC + sigmoid ----
    if (wr) hfin[b][jmine] = hreg;   // half0 only (half1 is garbage)
    __syncthreads();

    if (tid < BT * LSTM_OUT) {
        int bb = tid >> 3, o = tid & 7;
        float s = b_fc[o];
        #pragma unroll
        for (int j4 = 0; j4 < LSTM_H / 4; ++j4) {
            float4 wv = ld4(W_fc + o * LSTM_H + 4 * j4);
            float4 hv = *reinterpret_cast<const float4*>(&hfin[bb][4 * j4]);
            s = fmaf(wv.x, hv.x, s);
            s = fmaf(wv.y, hv.y, s);
            s = fmaf(wv.z, hv.z, s);
            s = fmaf(wv.w, hv.w, s);
        }
        out[(size_t)(bbase + bb) * LSTM_OUT + o] = sigm2(s * L2E);
    }
}

extern "C" void kernel_launch(void* const* d_in, const int* in_sizes, int n_in,
                              void* d_out, int out_size, void* d_ws, size_t ws_size,
                              hipStream_t stream) {
    const float* x    = (const float*)d_in[0];
    const float* W_ih = (const float*)d_in[1];
    const float* W_hh = (const float*)d_in[2];
    const float* b_ih = (const float*)d_in[3];
    const float* b_hh = (const float*)d_in[4];
    const float* W_fc = (const float*)d_in[5];
    const float* b_fc = (const float*)d_in[6];
    float* out = (float*)d_out;

    lstm_mfma_kernel<<<1024 / BT, 256, 0, stream>>>(
        x, W_ih, W_hh, b_ih, b_hh, W_fc, b_fc, out);
}

// Round 8
// 222.162 us; speedup vs baseline: 1.2794x; 1.0194x over previous
//
#include <hip/hip_runtime.h>
#include <math.h>

// LSTM B=1024,T=512,IN=16,H=64,OUT=8, gates i,f,g,o.
// R20: CONSTANT-FOLDED ADDRESSING. R18/R19 matched predictions: wall =
// total per-SIMD issue volume (854cyc/step: MFMA 304 + VALU 483 = 92%).
// MFMA(8/wave) and trans(6/wave) are at the decomposition floor; what's
// left deletable is addressing VALU + chain odds and ends.
//   1) outer loop unrolled to 16 steps (2 chunks) -> xw chunk-buf parity
//      compile-time -> all xw LDS addresses = precomputed per-lane VGPR
//      (xwp[8] read ptrs with XOR-k baked, xww[2][4] write ptrs) + imm
//      offset. Per-step addressing ~0 VALU.
//   2) half1 ships L2E2*tanh(g) (a1=L2E2, b1=-2*L2E2): the Ki mul rides
//      the DPP for free. Half1 garbage cs may hit +-inf -> dump row only.
//   3) unconditional h-write: half1 -> dump rows 2+b of hbuf[2][4][80];
//      per-wave banks {8w,8+8w,16+8w,24+8w} = all 32, 2 lanes/dword
//      same-dword (free). No exec toggle on the chain tail.
// Kept: spread xw burst, breadth-first h-MFMAs, time-batched xw chunks
// (pairs preloaded 1 step early), DPP lane^8 gate-pairing (6 trans/step),
// scales folded (i,f,o x -L2E; g x +L2E2; cs=L2E2*c), setprio, dbuf h,
// 1 lite barrier/step, 2 blocks/CU.

#define LSTM_T 512
#define LSTM_IN 16
#define LSTM_H 64
#define LSTM_OUT 8
#define BT 2
#define HSTRIDE 80   // halves per batch row; 4 rows (2 real + 2 dump)
#define HPSTR 320    // parity stride in halves = 4*HSTRIDE
#define XSTR 73      // float2 stride per (t&7, b, half) slot
#define XWSZ 2336    // >= 31*73 + 64

#define L2E   1.44269504088896340736f
#define L2E2  2.88539008177792681472f

typedef _Float16 half8  __attribute__((ext_vector_type(8)));
typedef float    floatx4 __attribute__((ext_vector_type(4)));

static __device__ __forceinline__ float fast_rcp(float x) { return __builtin_amdgcn_rcpf(x); }
static __device__ __forceinline__ float fast_exp2(float x) { return __builtin_amdgcn_exp2f(x); }
static __device__ __forceinline__ float sigm2(float p) { return fast_rcp(1.0f + fast_exp2(-p)); }
static __device__ __forceinline__ void pin4(int4& v) {
    asm volatile("" : "+v"(v.x), "+v"(v.y), "+v"(v.z), "+v"(v.w));
}
static __device__ __forceinline__ void pinf4(float4& v) {
    asm volatile("" : "+v"(v.x), "+v"(v.y), "+v"(v.z), "+v"(v.w));
}
static __device__ __forceinline__ void lite_barrier() {
    asm volatile("s_waitcnt lgkmcnt(0)\n\ts_barrier" ::: "memory");
}
static __device__ __forceinline__ unsigned pk2h(float a, float b) {
    return __builtin_bit_cast(unsigned, __builtin_amdgcn_cvt_pkrtz(a, b));
}
static __device__ __forceinline__ half8 to_h8(float4 a, float4 b) {
    uint4 u = make_uint4(pk2h(a.x, a.y), pk2h(a.z, a.w), pk2h(b.x, b.y), pk2h(b.z, b.w));
    return __builtin_bit_cast(half8, u);
}
static __device__ __forceinline__ int4 cvt8h(float4 a, float4 b) {
    return __builtin_bit_cast(int4, to_h8(a, b));
}
static __device__ __forceinline__ float4 ld4(const float* p) {
    return *reinterpret_cast<const float4*>(p);
}
static __device__ __forceinline__ float4 scl4(float4 v, float s) {
    return make_float4(s * v.x, s * v.y, s * v.z, s * v.w);
}
static __device__ __forceinline__ float sel4(floatx4 v, bool r0, bool r1) {
    float lo = r0 ? v[1] : v[0];
    float hi = r0 ? v[3] : v[2];
    return r1 ? hi : lo;
}
// lane^8 exchange via DPP row_ror:8 (full-rate VALU, no LDS pipe)
static __device__ __forceinline__ float dpp8(float v) {
    int r = __builtin_amdgcn_update_dpp(0, __builtin_bit_cast(int, v),
                                        0x128, 0xF, 0xF, false);
    return __builtin_bit_cast(float, r);
}

#define MF(A_, B_, C_) __builtin_amdgcn_mfma_f32_16x16x32_f16( \
        __builtin_bit_cast(half8, A_), (B_), (C_), 0, 0, 0)
#define B4(i) __builtin_bit_cast(floatx4, bias4[i])

__global__ __launch_bounds__(256, 2)
void lstm_mfma_kernel(const float* __restrict__ x,
                      const float* __restrict__ W_ih,
                      const float* __restrict__ W_hh,
                      const float* __restrict__ b_ih,
                      const float* __restrict__ b_hh,
                      const float* __restrict__ W_fc,
                      const float* __restrict__ b_fc,
                      float* __restrict__ out) {
    const int tid   = threadIdx.x;
    const int lane  = tid & 63;
    const int w     = tid >> 6;        // wave -> j-slice [16w, 16w+16)
    const int q     = lane >> 4;       // k-quad / C row group
    const int m     = lane & 15;       // A row-in-tile / B col / C col
    const int b     = m & 1;           // real batch
    const int dt    = m >> 1;          // burst col -> timestep-in-chunk
    const int rho   = (m >> 1) & 3;    // replica id -> C row r to activate
    const bool r0   = (rho & 1) != 0;
    const bool r1   = (rho & 2) != 0;
    const bool h1   = (m & 8) != 0;    // gate-pair half: 0 = f/i, 1 = g/o
    const int h1i   = h1 ? 1 : 0;
    const bool wr   = (m < 8);         // half0 holds the valid c/h state
    const int jmine = 16 * w + 4 * q + rho;
    const int bbase = blockIdx.x * BT;

    // half0: act1 = sigma(f); half1: act1 = L2E2*tanh(g) (Ki rides the DPP)
    const float a1 = h1 ? L2E2 : 0.0f;
    const float b1 = h1 ? (-2.0f * L2E2) : 1.0f;

    __shared__ __align__(16)  float2   xwbuf[2][XWSZ];        // xw chunks
    __shared__ __align__(128) _Float16 hbuf[2][2 * BT][HSTRIDE]; // h + dump
    __shared__ __align__(16)  float    hfin[BT][LSTM_H];      // final h

    // ---- weights as pinned fp16 A-fragments, act scales PRE-FOLDED ----
    int4 Ah[4][2], Ax[4];
    float4 bias4[4];
    #pragma unroll
    for (int tt = 0; tt < 4; ++tt) {
        const float sc = (tt == 2) ? L2E2 : -L2E;
        const int gt = tt * 64 + 16 * w + m;
        #pragma unroll
        for (int c = 0; c < 2; ++c) {
            const float* s = W_hh + gt * LSTM_H + 32 * c + 8 * q;
            Ah[tt][c] = cvt8h(scl4(ld4(s), sc), scl4(ld4(s + 4), sc));
            pin4(Ah[tt][c]);
        }
        float4 xa = make_float4(0.f, 0.f, 0.f, 0.f), xb = xa;
        if (q < 2) {
            const float* s = W_ih + gt * LSTM_IN + 8 * q;
            xa = ld4(s); xb = ld4(s + 4);
        }
        Ax[tt] = cvt8h(scl4(xa, sc), scl4(xb, sc));
        pin4(Ax[tt]);
        const int gb = tt * 64 + 16 * w + 4 * q;
        float4 bi = ld4(b_ih + gb), bh = ld4(b_hh + gb);
        bias4[tt] = make_float4(sc * (bi.x + bh.x), sc * (bi.y + bh.y),
                                sc * (bi.z + bh.z), sc * (bi.w + bh.w));
        pinf4(bias4[tt]);
    }

    float4 zc4 = make_float4(0.f, 0.f, 0.f, 0.f);
    pinf4(zc4);
    const floatx4 zc = __builtin_bit_cast(floatx4, zc4);

    // ---- precomputed LDS pointers (all per-step addressing folds away) --
    const float2* xwp[8];      // read ptrs, XOR-k baked in
    #pragma unroll
    for (int k = 0; k < 8; ++k)
        xwp[k] = &xwbuf[0][(2 * b + h1i) * XSTR + (jmine ^ k)];
    float2* xww[2][4];         // burst write ptrs
    #pragma unroll
    for (int pr = 0; pr < 2; ++pr)
        #pragma unroll
        for (int r = 0; r < 4; ++r)
            xww[pr][r] = &xwbuf[0][(dt * 4 + 2 * b + pr) * XSTR
                                   + ((16 * w + 4 * q + r) ^ dt)];
    const _Float16* hrp = &hbuf[0][b][8 * q];
    _Float16*       hwp = &hbuf[0][h1 ? 2 + b : b][jmine];

    // ---- zero hbuf[0] (h_{-1}=0): 4 rows * 80 halves = 160 dwords ----
    if (tid < 160) reinterpret_cast<int*>(&hbuf[0][0][0])[tid] = 0;

    // ---- burst x pointer: lane covers (b, t0+dt), elems 8q..8q+7 ----
    const float* xpb = x + (size_t)(bbase + b) * LSTM_T * LSTM_IN
                         + (size_t)dt * LSTM_IN + 8 * q;
    float4 Xb0 = make_float4(0.f, 0.f, 0.f, 0.f), Xb1 = Xb0;
    if (q < 2) { Xb0 = ld4(xpb); Xb1 = ld4(xpb + 4); }   // chunk 0

// burst LDS write of pair PR (0=(f,i),1=(g,o)), rows R_,R_+1, into buf WB
#define BWR(WB, PR, R_)                                                         \
    xww[PR][R_][(WB) * XWSZ] = (PR)                                             \
        ? make_float2(aXg_[R_], aXo_[R_])                                       \
        : make_float2(aXf_[R_], aXi_[R_]);                                      \
    xww[PR][(R_) + 1][(WB) * XWSZ] = (PR)                                       \
        ? make_float2(aXg_[(R_) + 1], aXo_[(R_) + 1])                           \
        : make_float2(aXf_[(R_) + 1], aXi_[(R_) + 1]);

    // ---- prologue: chunk0 (steps 0..7) -> xwbuf[0] ----
    floatx4 aXi_, aXf_, aXg_, aXo_;
    half8 xfb;
    {
        half8 x0 = to_h8(Xb0, Xb1);
        aXi_ = MF(Ax[0], x0, B4(0));
        aXf_ = MF(Ax[1], x0, B4(1));
        aXg_ = MF(Ax[2], x0, B4(2));
        aXo_ = MF(Ax[3], x0, B4(3));
        BWR(0, 0, 0) BWR(0, 0, 2) BWR(0, 1, 0) BWR(0, 1, 2)
    }
    if (q < 2) {   // x for chunk 1 (steps 8..15)
        Xb0 = ld4(xpb + 8 * LSTM_IN);
        Xb1 = ld4(xpb + 8 * LSTM_IN + 4);
    }
    __syncthreads();   // hbuf zeros + chunk0 visible

    float2 xwc = xwp[0][0];          // t=0 pair
    float cs = 0.0f, hreg = 0.0f;    // cs = L2E2 * c (half0 valid)

// PK = hbuf parity (literal), KN = next step's k (literal), NC = next
// step's chunk buf (literal). __VA_ARGS__ = spread-burst micro-op.
#define STEP_CORE(PK, KN, NC, ...)                                              \
    {                                                                           \
        half8 bh0 = *reinterpret_cast<const half8*>(hrp + (PK) * HPSTR);        \
        half8 bh1 = *reinterpret_cast<const half8*>(hrp + (PK) * HPSTR + 32);   \
        __VA_ARGS__                                                             \
        /* preload next step's xw pair: ptr + imm only */                       \
        float2 xwn = xwp[KN][(NC) * XWSZ + (KN) * 4 * XSTR];                    \
        /* breadth-first h-MFMAs: all dep gaps >= 3 (no stall) */               \
        floatx4 accf = MF(Ah[1][0], bh0, zc);                                   \
        floatx4 accg = MF(Ah[2][0], bh0, zc);                                   \
        floatx4 acci = MF(Ah[0][0], bh0, zc);                                   \
        floatx4 acco = MF(Ah[3][0], bh0, zc);                                   \
        accf = MF(Ah[1][1], bh1, accf);                                         \
        accg = MF(Ah[2][1], bh1, accg);                                         \
        __builtin_amdgcn_s_setprio(1);                                          \
        float uf = sel4(accf, r0, r1);                                          \
        float ug = sel4(accg, r0, r1);                                          \
        float u1 = (h1 ? ug : uf) + xwc.x;                                      \
        float e1 = fast_exp2(u1);                                               \
        acci = MF(Ah[0][1], bh1, acci);                                         \
        acco = MF(Ah[3][1], bh1, acco);                                         \
        /* act1: sigma(f) on half0; L2E2*tanh(g) on half1 */                    \
        float act1 = fmaf(b1, fast_rcp(1.0f + e1), a1);                         \
        float uii = sel4(acci, r0, r1);                                         \
        float uoo = sel4(acco, r0, r1);                                         \
        float u2 = (h1 ? uoo : uii) + xwc.y;                                    \
        float e2 = fast_exp2(u2);                                               \
        float act2 = fast_rcp(1.0f + e2);    /* sigma(i) h0, sigma(o) h1 */     \
        float g_in = dpp8(act1);             /* h0 gets L2E2*tanh(g) */         \
        float o_in = dpp8(act2);             /* h0 gets sigma(o) */             \
        /* canonical on half0; half1 garbage -> dump row (never read) */        \
        cs = fmaf(act1, cs, act2 * g_in);                                       \
        float E  = fast_exp2(cs);                                               \
        float r_ = fast_rcp(1.0f + E);                                          \
        float n2o = -2.0f * o_in;            /* under rcp latency */            \
        hreg = fmaf(n2o, r_, o_in);          /* o * tanh(cs) */                 \
        hwp[((PK) ^ 1) * HPSTR] = (_Float16)hreg;   /* unconditional */         \
        __builtin_amdgcn_s_setprio(0);                                          \
        lite_barrier();                                                         \
        xwc = xwn;                                                              \
    }

    for (int t16 = 0; t16 < LSTM_T; t16 += 16) {
        const bool more = (t16 + 16) < LSTM_T;
        // ---- sub-chunk A: steps t16+0..7, xw buf0, produce buf1 ----
        STEP_CORE(0, 1, 0,
            { xfb = to_h8(Xb0, Xb1); aXi_ = MF(Ax[0], xfb, B4(0)); })
        STEP_CORE(1, 2, 0, { aXf_ = MF(Ax[1], xfb, B4(1)); })
        STEP_CORE(0, 3, 0, { aXg_ = MF(Ax[2], xfb, B4(2)); })
        STEP_CORE(1, 4, 0, { aXo_ = MF(Ax[3], xfb, B4(3)); })
        STEP_CORE(0, 5, 0, { BWR(1, 0, 0) })
        STEP_CORE(1, 6, 0, { BWR(1, 0, 2) })
        STEP_CORE(0, 7, 0, { BWR(1, 1, 0)
            if (q < 2 && more) Xb0 = ld4(xpb + (size_t)(t16 + 16) * LSTM_IN); })
        STEP_CORE(1, 0, 1, { BWR(1, 1, 2)
            if (q < 2 && more) Xb1 = ld4(xpb + (size_t)(t16 + 16) * LSTM_IN + 4); })
        // ---- sub-chunk B: steps t16+8..15, xw buf1, produce buf0 ----
        STEP_CORE(0, 1, 1,
            { if (more) { xfb = to_h8(Xb0, Xb1); aXi_ = MF(Ax[0], xfb, B4(0)); } })
        STEP_CORE(1, 2, 1, { if (more) { aXf_ = MF(Ax[1], xfb, B4(1)); } })
        STEP_CORE(0, 3, 1, { if (more) { aXg_ = MF(Ax[2], xfb, B4(2)); } })
        STEP_CORE(1, 4, 1, { if (more) { aXo_ = MF(Ax[3], xfb, B4(3)); } })
        STEP_CORE(0, 5, 1, { if (more) { BWR(0, 0, 0) } })
        STEP_CORE(1, 6, 1, { if (more) { BWR(0, 0, 2) } })
        STEP_CORE(0, 7, 1, { if (more) { BWR(0, 1, 0) }
            if (q < 2 && more) Xb0 = ld4(xpb + (size_t)(t16 + 24) * LSTM_IN); })
        STEP_CORE(1, 0, 0, { if (more) { BWR(0, 1, 2) }
            if (q < 2 && more) Xb1 = ld4(xpb + (size_t)(t16 + 24) * LSTM_IN + 4); })
    }
#undef STEP_CORE
#undef BWR

    // ---- final h (fp32) -> LDS, then FC + sigmoid ----
    if (wr) hfin[b][jmine] = hreg;   // half0 only (half1 is garbage)
    __syncthreads();

    if (tid < BT * LSTM_OUT) {
        int bb = tid >> 3, o = tid & 7;
        float s = b_fc[o];
        #pragma unroll
        for (int j4 = 0; j4 < LSTM_H / 4; ++j4) {
            float4 wv = ld4(W_fc + o * LSTM_H + 4 * j4);
            float4 hv = *reinterpret_cast<const float4*>(&hfin[bb][4 * j4]);
            s = fmaf(wv.x, hv.x, s);
            s = fmaf(wv.y, hv.y, s);
            s = fmaf(wv.z, hv.z, s);
            s = fmaf(wv.w, hv.w, s);
        }
        out[(size_t)(bbase + bb) * LSTM_OUT + o] = sigm2(s * L2E);
    }
}

extern "C" void kernel_launch(void* const* d_in, const int* in_sizes, int n_in,
                              void* d_out, int out_size, void* d_ws, size_t ws_size,
                              hipStream_t stream) {
    const float* x    = (const float*)d_in[0];
    const float* W_ih = (const float*)d_in[1];
    const float* W_hh = (const float*)d_in[2];
    const float* b_ih = (const float*)d_in[3];
    const float* b_hh = (const float*)d_in[4];
    const float* W_fc = (const float*)d_in[5];
    const float* b_fc = (const float*)d_in[6];
    float* out = (float*)d_out;

    lstm_mfma_kernel<<<1024 / BT, 256, 0, stream>>>(
        x, W_ih, W_hh, b_ih, b_hh, W_fc, b_fc, out);
}